// Round 2
// baseline (352.721 us; speedup 1.0000x reference)
//
#include <hip/hip_runtime.h>

// FernSparseTable: B[64,160,32,32] f32 bit-probs, tables[16,1024,64] f32.
// out[64,32,32,64] f32 = sum over 16 ferns of 8-word weighted table gathers.
//
// Thread = (pixel, d-quarter). 65536 pixels x 4 quarters -> 1024 blocks x 256.
// Per word each thread gathers exactly one 64B line (4 x float4).
// Block mapping: bp = blockIdx&255, dq = blockIdx>>8 so the 4 blocks sharing
// a pixel range land on the same XCD (bp, bp+256, bp+512, bp+768 = bp mod 8).

#define NFERN 16
#define KBITS 10

__global__ __launch_bounds__(256, 4)
void fern_kernel(const float* __restrict__ B,
                 const float* __restrict__ tables,
                 float* __restrict__ out) {
    const int bp    = blockIdx.x & 255;     // pixel block 0..255
    const int dq    = blockIdx.x >> 8;      // d quarter: 0..3 -> 16 floats each
    const int pixel = bp * 256 + (int)threadIdx.x;   // 0..65535
    const int n     = pixel >> 10;          // image index
    const int hw    = pixel & 1023;         // h*32+w

    const float* bptr = B + (size_t)n * (NFERN * KBITS * 1024) + hw;
    const float* tab  = tables + dq * 16;

    float4 acc[4];
    #pragma unroll
    for (int q = 0; q < 4; ++q) acc[q] = make_float4(0.f, 0.f, 0.f, 0.f);

    #pragma unroll 1
    for (int m = 0; m < NFERN; ++m) {
        // ---- load the 10 bit probabilities for this fern (coalesced) ----
        float t[KBITS];
        #pragma unroll
        for (int k = 0; k < KBITS; ++k)
            t[k] = bptr[(m * KBITS + k) * 1024];

        // ---- base word + ambiguity ----
        unsigned wb = 0u;
        float ba[KBITS];
        #pragma unroll
        for (int k = 0; k < KBITS; ++k) {
            // jnp.round: round-half-even -> exactly 0.5 rounds to 0, so strict >
            wb = (wb << 1) | (t[k] > 0.5f ? 1u : 0u);
            ba[k] = fabsf(t[k] - 0.5f);
        }

        // ---- three argmin passes (first-occurrence on ties, exclude by index) ----
        int i0, i1, i2;
        float p0, p1, p2;
        {
            float bv = 1e30f; int bi = 0; float bpv = 0.f;
            #pragma unroll
            for (int k = 0; k < KBITS; ++k) {
                bool c = ba[k] < bv;
                bv  = c ? ba[k] : bv;
                bi  = c ? k     : bi;
                bpv = c ? t[k]  : bpv;
            }
            i0 = bi; p0 = bpv;
        }
        {
            float bv = 1e30f; int bi = 0; float bpv = 0.f;
            #pragma unroll
            for (int k = 0; k < KBITS; ++k) {
                float v = (k == i0) ? 1e30f : ba[k];
                bool c = v < bv;
                bv  = c ? v    : bv;
                bi  = c ? k    : bi;
                bpv = c ? t[k] : bpv;
            }
            i1 = bi; p1 = bpv;
        }
        {
            float bv = 1e30f; int bi = 0; float bpv = 0.f;
            #pragma unroll
            for (int k = 0; k < KBITS; ++k) {
                float v = (k == i0 || k == i1) ? 1e30f : ba[k];
                bool c = v < bv;
                bv  = c ? v    : bv;
                bi  = c ? k    : bi;
                bpv = c ? t[k] : bpv;
            }
            i2 = bi; p2 = bpv;
        }

        const unsigned m0 = 1u << (KBITS - 1 - i0);
        const unsigned m1 = 1u << (KBITS - 1 - i1);
        const unsigned m2 = 1u << (KBITS - 1 - i2);
        const float q0 = 1.f - p0, q1 = 1.f - p1, q2 = 1.f - p2;

        const float* tabm = tab + (size_t)m * (1024 * 64);

        // ---- 8 active words: gather one 64B line + weighted accumulate ----
        #pragma unroll
        for (int a = 0; a < 8; ++a) {
            unsigned it = wb;
            float at = 1.f;
            if (a & 1) { it |= m0; at *= p0; } else { it &= ~m0; at *= q0; }
            if (a & 2) { it |= m1; at *= p1; } else { it &= ~m1; at *= q1; }
            if (a & 4) { it |= m2; at *= p2; } else { it &= ~m2; at *= q2; }
            const float4* row = (const float4*)(tabm + (size_t)it * 64);
            #pragma unroll
            for (int q = 0; q < 4; ++q) {
                float4 v = row[q];
                acc[q].x = fmaf(at, v.x, acc[q].x);
                acc[q].y = fmaf(at, v.y, acc[q].y);
                acc[q].z = fmaf(at, v.z, acc[q].z);
                acc[q].w = fmaf(at, v.w, acc[q].w);
            }
        }
    }

    // ---- store out[pixel, dq*16 .. dq*16+15] ----
    float4* op = (float4*)(out + (size_t)pixel * 64 + dq * 16);
    #pragma unroll
    for (int q = 0; q < 4; ++q) op[q] = acc[q];
}

extern "C" void kernel_launch(void* const* d_in, const int* in_sizes, int n_in,
                              void* d_out, int out_size, void* d_ws, size_t ws_size,
                              hipStream_t stream) {
    const float* B      = (const float*)d_in[0];
    const float* tables = (const float*)d_in[1];
    float* out          = (float*)d_out;
    fern_kernel<<<dim3(1024), dim3(256), 0, stream>>>(B, tables, out);
}

// Round 3
// 165.661 us; speedup vs baseline: 2.1292x; 2.1292x over previous
//
#include <hip/hip_runtime.h>

// FernSparseTable: B[64,160,32,32] f32 bit-probs, tables[16,1024,64] f32.
// out[64,32,32,64] f32 = sum over 16 ferns of 8-word weighted table gathers.
//
// Quad-cooperative gather layout: 4 threads per pixel (s = lane&3).
// Per gather instruction (fixed word a, fixed j), the 4 lanes of a pixel read
// consecutive 16B of the SAME 64B line: addr = it*256 + j*64 + s*16.
// -> 16 distinct cache lines per 64-lane instruction instead of 64 (4x less
// TA serialization, which round-2 counters showed to be the bottleneck).
// Thread (pixel, s) owns out d-positions { j*16 + s*4 .. +3 : j=0..3 }.

#define NFERN 16
#define KBITS 10

__global__ __launch_bounds__(256, 4)
void fern_kernel(const float* __restrict__ B,
                 const float* __restrict__ tables,
                 float* __restrict__ out) {
    const int t  = (int)threadIdx.x;
    const int s  = t & 3;                    // 16B sub-slice within a 64B line
    const int pl = t >> 2;                   // local pixel 0..63
    const int pixel = (int)blockIdx.x * 64 + pl;   // 0..65535
    const int n  = pixel >> 10;              // image index (64 px/block -> uniform n)
    const int hw = pixel & 1023;             // h*32+w

    const float* bptr = B + (size_t)n * (NFERN * KBITS * 1024) + hw;

    float4 acc[4];                           // acc[j] -> out d = j*16 + s*4 .. +3
    #pragma unroll
    for (int j = 0; j < 4; ++j) acc[j] = make_float4(0.f, 0.f, 0.f, 0.f);

    #pragma unroll 1
    for (int m = 0; m < NFERN; ++m) {
        // ---- load the 10 bit probabilities for this fern ----
        // (16 consecutive addresses x broadcast-4 per wave -> 1 line/instr)
        float tk[KBITS];
        #pragma unroll
        for (int k = 0; k < KBITS; ++k)
            tk[k] = bptr[(m * KBITS + k) * 1024];

        // ---- base word + ambiguity ----
        unsigned wb = 0u;
        float ba[KBITS];
        #pragma unroll
        for (int k = 0; k < KBITS; ++k) {
            // jnp.round: round-half-even -> exactly 0.5 rounds to 0, so strict >
            wb = (wb << 1) | (tk[k] > 0.5f ? 1u : 0u);
            ba[k] = fabsf(tk[k] - 0.5f);
        }

        // ---- three argmin passes (first-occurrence ties, exclude by index) ----
        int i0, i1, i2;
        float p0, p1, p2;
        {
            float bv = 1e30f; int bi = 0; float bpv = 0.f;
            #pragma unroll
            for (int k = 0; k < KBITS; ++k) {
                bool c = ba[k] < bv;
                bv  = c ? ba[k] : bv;
                bi  = c ? k      : bi;
                bpv = c ? tk[k]  : bpv;
            }
            i0 = bi; p0 = bpv;
        }
        {
            float bv = 1e30f; int bi = 0; float bpv = 0.f;
            #pragma unroll
            for (int k = 0; k < KBITS; ++k) {
                float v = (k == i0) ? 1e30f : ba[k];
                bool c = v < bv;
                bv  = c ? v     : bv;
                bi  = c ? k     : bi;
                bpv = c ? tk[k] : bpv;
            }
            i1 = bi; p1 = bpv;
        }
        {
            float bv = 1e30f; int bi = 0; float bpv = 0.f;
            #pragma unroll
            for (int k = 0; k < KBITS; ++k) {
                float v = (k == i0 || k == i1) ? 1e30f : ba[k];
                bool c = v < bv;
                bv  = c ? v     : bv;
                bi  = c ? k     : bi;
                bpv = c ? tk[k] : bpv;
            }
            i2 = bi; p2 = bpv;
        }

        const unsigned m0 = 1u << (KBITS - 1 - i0);
        const unsigned m1 = 1u << (KBITS - 1 - i1);
        const unsigned m2 = 1u << (KBITS - 1 - i2);
        const float q0 = 1.f - p0, q1 = 1.f - p1, q2 = 1.f - p2;

        const float* tabm = tables + (size_t)m * (1024 * 64) + s * 4;

        // ---- 8 active words: quad-cooperative gather + weighted accumulate ----
        #pragma unroll
        for (int a = 0; a < 8; ++a) {
            unsigned it = wb;
            float at = 1.f;
            if (a & 1) { it |= m0; at *= p0; } else { it &= ~m0; at *= q0; }
            if (a & 2) { it |= m1; at *= p1; } else { it &= ~m1; at *= q1; }
            if (a & 4) { it |= m2; at *= p2; } else { it &= ~m2; at *= q2; }
            const float* row = tabm + (size_t)it * 64;   // + j*16 below
            #pragma unroll
            for (int j = 0; j < 4; ++j) {
                float4 v = *(const float4*)(row + j * 16);
                acc[j].x = fmaf(at, v.x, acc[j].x);
                acc[j].y = fmaf(at, v.y, acc[j].y);
                acc[j].z = fmaf(at, v.z, acc[j].z);
                acc[j].w = fmaf(at, v.w, acc[j].w);
            }
        }
    }

    // ---- store: same quad-cooperative pattern (16 lines/instr) ----
    float* op = out + (size_t)pixel * 64 + s * 4;
    #pragma unroll
    for (int j = 0; j < 4; ++j)
        *(float4*)(op + j * 16) = acc[j];
}

extern "C" void kernel_launch(void* const* d_in, const int* in_sizes, int n_in,
                              void* d_out, int out_size, void* d_ws, size_t ws_size,
                              hipStream_t stream) {
    const float* B      = (const float*)d_in[0];
    const float* tables = (const float*)d_in[1];
    float* out          = (float*)d_out;
    fern_kernel<<<dim3(1024), dim3(256), 0, stream>>>(B, tables, out);
}